// Round 2
// baseline (166.652 us; speedup 1.0000x reference)
//
#include <hip/hip_runtime.h>

#define NB 512
#define NN 50
#define ND 64

__device__ __forceinline__ float bflo(unsigned int w) {
    union { unsigned int i; float f; } v; v.i = w << 16; return v.f;
}
__device__ __forceinline__ float bfhi(unsigned int w) {
    union { unsigned int i; float f; } v; v.i = w & 0xFFFF0000u; return v.f;
}
__device__ __forceinline__ float bfu(unsigned short u) {
    union { unsigned int i; float f; } v; v.i = ((unsigned int)u) << 16; return v.f;
}
// fp32 -> bf16 bits, round-to-nearest-even
__device__ __forceinline__ unsigned int f2bfbits(float f) {
    union { float f; unsigned int i; } v; v.f = f;
    unsigned int x = v.i;
    return (x + 0x7FFFu + ((x >> 16) & 1u)) >> 16;
}

// One block per batch. 256 threads: d = tid&63, iq = tid>>6; thread owns rows i = iq+4r.
__global__ __launch_bounds__(256, 2)
void att2_kernel(const float* __restrict__ emb,
                 const float* __restrict__ wa1, const float* __restrict__ ba1,
                 const float* __restrict__ wa2, const float* __restrict__ ba2,
                 const float* __restrict__ w1,  const float* __restrict__ b1,
                 const float* __restrict__ w2,  const float* __restrict__ b2,
                 float* __restrict__ out)
{
    __shared__ __align__(16) float xs[NN * ND];   // layer input x (fp32)
    __shared__ __align__(16) float qs[NN * ND];   // q, then reused for att (pre-gemm)
    __shared__ __align__(16) float ks[NN * ND];   // k
    __shared__ unsigned int   wqk[ND * ND];       // lo16 = bf16(Wa1), hi16 = bf16(Wa2)
    __shared__ unsigned short wo[ND * ND];        // bf16(W1) for L0, bf16(W2) for L1

    const int b   = blockIdx.x;
    const int tid = threadIdx.x;
    const int d   = tid & 63;
    const int iq  = tid >> 6;

    const float* embB = emb + (size_t)b * (NN + 1) * ND;

    // ---- phase 0: stage x = i_em (vectorized), pack Wa1/Wa2, stage W1 ----
    {
        const float4* src4 = (const float4*)(embB + ND);   // 64-float aligned
        float4*       dst4 = (float4*)xs;
        for (int idx = tid; idx < (NN * ND) / 4; idx += 256)
            dst4[idx] = src4[idx];
    }
    for (int idx = tid; idx < ND * ND; idx += 256) {
        wqk[idx] = (f2bfbits(wa2[idx]) << 16) | f2bfbits(wa1[idx]);
        wo[idx]  = (unsigned short)f2bfbits(w1[idx]);
    }
    __syncthreads();

    const float bq  = ba1[d];
    const float bk  = ba2[d];
    const float bo1 = b1[d];
    const float bo2 = b2[d];

    for (int L = 0; L < 2; ++L) {
        // ---- phase 1: q/k GEMM (restage wo = W2 on L==1; its previous readers
        //      finished before the barrier at the end of L0 phase 3; its next
        //      readers are two barriers ahead) ----
        if (L == 1) {
            for (int idx = tid; idx < ND * ND; idx += 256)
                wo[idx] = (unsigned short)f2bfbits(w2[idx]);
        }
        for (int r = 0; r < 13; ++r) {
            int i = iq + 4 * r;
            if (i >= NN) break;                 // wave-uniform (iq uniform per wave)
            float aq = bq, ak = bk;
            const float4* xrow = (const float4*)&xs[i * ND];
#pragma unroll
            for (int cb = 0; cb < 16; ++cb) {
                float4 xv = xrow[cb];
#pragma unroll
                for (int u = 0; u < 4; ++u) {
                    unsigned int w = wqk[(cb * 4 + u) * ND + d];
                    float xc = ((const float*)&xv)[u];
                    aq = fmaf(bflo(w), xc, aq);
                    ak = fmaf(bfhi(w), xc, ak);
                }
            }
            qs[i * ND + d] = aq;
            ks[i * ND + d] = ak;
        }
        __syncthreads();

        // ---- phase 2: per-(i,d) 50-way softmax-weighted sum over j ----
        // att[i,d] = sum_j exp(lrelu(q[i,d]+k[j,d])) * x[j,d] / sum_j exp(...)
        // In-place overwrite of qs[i,d]: sole reader/writer is this thread.
        for (int r = 0; r < 13; ++r) {
            int i = iq + 4 * r;
            if (i >= NN) break;
            float qv  = qs[i * ND + d];
            float den = 0.f, num = 0.f;
            for (int j = 0; j < NN; ++j) {
                float z = qv + ks[j * ND + d];
                z = fmaxf(z, 0.01f * z);        // leaky_relu, slope 0.01
                float w = __expf(z);            // |z| bounded (~8): no max-subtraction needed
                den += w;
                num = fmaf(w, xs[j * ND + d], num);
            }
            qs[i * ND + d] = num / den;
        }
        __syncthreads();

        // ---- phase 3: output GEMM y = att @ Wl + bl ----
        if (L == 0) {
            for (int r = 0; r < 13; ++r) {
                int i = iq + 4 * r;
                if (i >= NN) break;
                float acc = bo1;
                const float4* arow = (const float4*)&qs[i * ND];
#pragma unroll
                for (int cb = 0; cb < 16; ++cb) {
                    float4 av = arow[cb];
#pragma unroll
                    for (int u = 0; u < 4; ++u)
                        acc = fmaf(bfu(wo[(cb * 4 + u) * ND + d]),
                                   ((const float*)&av)[u], acc);
                }
                xs[i * ND + d] = acc;           // layer-2 input AND att1 residual
            }
            __syncthreads();
        } else {
            const float e0 = embB[d];           // embeddings[b,0,d]
            for (int r = 0; r < 13; ++r) {
                int i = iq + 4 * r;
                if (i >= NN) break;
                float acc = bo2;
                const float4* arow = (const float4*)&qs[i * ND];
#pragma unroll
                for (int cb = 0; cb < 16; ++cb) {
                    float4 av = arow[cb];
#pragma unroll
                    for (int u = 0; u < 4; ++u)
                        acc = fmaf(bfu(wo[(cb * 4 + u) * ND + d]),
                                   ((const float*)&av)[u], acc);
                }
                float ie = embB[ND + i * ND + d];         // i_em[i,d]
                float o  = fmaf(e0, ie, acc + xs[i * ND + d]);
                o = fmaxf(o, 0.01f * o);                   // final leaky_relu
                out[((size_t)b * NN + i) * ND + d] = o;
            }
        }
    }
}

extern "C" void kernel_launch(void* const* d_in, const int* in_sizes, int n_in,
                              void* d_out, int out_size, void* d_ws, size_t ws_size,
                              hipStream_t stream) {
    const float* emb = (const float*)d_in[0];
    const float* wa1 = (const float*)d_in[1];
    const float* ba1 = (const float*)d_in[2];
    const float* wa2 = (const float*)d_in[3];
    const float* ba2 = (const float*)d_in[4];
    const float* w1  = (const float*)d_in[5];
    const float* b1  = (const float*)d_in[6];
    const float* w2  = (const float*)d_in[7];
    const float* b2  = (const float*)d_in[8];
    float* out = (float*)d_out;

    att2_kernel<<<NB, 256, 0, stream>>>(emb, wa1, ba1, wa2, ba2, w1, b1, w2, b2, out);
}

// Round 3
// 148.879 us; speedup vs baseline: 1.1194x; 1.1194x over previous
//
#include <hip/hip_runtime.h>

#define NB 512
#define NN 50
#define ND 64
#define LOG2E 1.44269504088896340736f

__device__ __forceinline__ float bflo(unsigned int w) {
    union { unsigned int i; float f; } v; v.i = w << 16; return v.f;
}
__device__ __forceinline__ float bfhi(unsigned int w) {
    union { unsigned int i; float f; } v; v.i = w & 0xFFFF0000u; return v.f;
}
// fp32 -> bf16 bits, round-to-nearest-even
__device__ __forceinline__ unsigned int f2bfbits(float f) {
    union { float f; unsigned int i; } v; v.f = f;
    unsigned int x = v.i;
    return (x + 0x7FFFu + ((x >> 16) & 1u)) >> 16;
}

// One block per batch, 512 threads (8 waves): d = tid&63, iq = tid>>6 (0..7).
// Thread owns rows i = iq + 8r; r=0..5 always valid (i<=47+? max iq=7 -> 47), r=6 iff iq<2.
__global__ __launch_bounds__(512, 4)
void att2_kernel(const float* __restrict__ emb,
                 const float* __restrict__ wa1, const float* __restrict__ ba1,
                 const float* __restrict__ wa2, const float* __restrict__ ba2,
                 const float* __restrict__ w1,  const float* __restrict__ b1,
                 const float* __restrict__ w2,  const float* __restrict__ b2,
                 float* __restrict__ out)
{
    __shared__ __align__(16) float xs[NN * ND];       // layer input x
    __shared__ __align__(16) float qs[NN * ND];       // q*log2e, then att
    __shared__ __align__(16) float ks[NN * ND];       // k*log2e
    __shared__ unsigned int wqk[ND * ND];             // lo16=bf16(Wa1), hi16=bf16(Wa2)
    __shared__ unsigned int wo32[(ND / 2) * ND];      // pair-packed bf16(W1|W2): [(c/2)*64+d] lo=c, hi=c+1

    const int b   = blockIdx.x;
    const int tid = threadIdx.x;
    const int d   = tid & 63;
    const int iq  = tid >> 6;
    const bool has7 = (iq < 2);

    const float* embB = emb + (size_t)b * (NN + 1) * ND;

    // ---- phase 0: stage x, pack Wa1/Wa2, pack W1 ----
    {
        const float4* s4 = (const float4*)(embB + ND);
        float4* d4 = (float4*)xs;
        for (int idx = tid; idx < (NN * ND) / 4; idx += 512) d4[idx] = s4[idx];
    }
    for (int idx = tid; idx < ND * ND; idx += 512)
        wqk[idx] = (f2bfbits(wa2[idx]) << 16) | f2bfbits(wa1[idx]);
    for (int idx = tid; idx < (ND / 2) * ND; idx += 512) {
        int c2 = idx >> 6, dd = idx & 63;
        wo32[idx] = (f2bfbits(w1[(2 * c2 + 1) * ND + dd]) << 16)
                  |  f2bfbits(w1[(2 * c2) * ND + dd]);
    }
    __syncthreads();

    const float bq  = ba1[d];
    const float bk  = ba2[d];
    const float bo1 = b1[d];
    const float bo2 = b2[d];

    for (int L = 0; L < 2; ++L) {
        // ---- restage wo32 = W2 for L1 (old readers finished before last barrier;
        //      new readers are one barrier ahead) ----
        if (L == 1) {
            for (int idx = tid; idx < (ND / 2) * ND; idx += 512) {
                int c2 = idx >> 6, dd = idx & 63;
                wo32[idx] = (f2bfbits(w2[(2 * c2 + 1) * ND + dd]) << 16)
                          |  f2bfbits(w2[(2 * c2) * ND + dd]);
            }
        }

        // ---- phase 1: q/k GEMM, rows register-blocked, weights hoisted ----
        {
            float aq[7], ak[7];
#pragma unroll
            for (int r = 0; r < 7; ++r) { aq[r] = bq; ak[r] = bk; }
#pragma unroll
            for (int cb = 0; cb < 16; ++cb) {
                unsigned int u0 = wqk[(4 * cb + 0) * ND + d];
                unsigned int u1 = wqk[(4 * cb + 1) * ND + d];
                unsigned int u2 = wqk[(4 * cb + 2) * ND + d];
                unsigned int u3 = wqk[(4 * cb + 3) * ND + d];
                float q0 = bflo(u0), q1 = bflo(u1), q2 = bflo(u2), q3 = bflo(u3);
                float k0 = bfhi(u0), k1 = bfhi(u1), k2 = bfhi(u2), k3 = bfhi(u3);
#pragma unroll
                for (int r = 0; r < 6; ++r) {
                    float4 xv = ((const float4*)&xs[(iq + 8 * r) * ND])[cb];
                    aq[r] = fmaf(q0, xv.x, aq[r]); aq[r] = fmaf(q1, xv.y, aq[r]);
                    aq[r] = fmaf(q2, xv.z, aq[r]); aq[r] = fmaf(q3, xv.w, aq[r]);
                    ak[r] = fmaf(k0, xv.x, ak[r]); ak[r] = fmaf(k1, xv.y, ak[r]);
                    ak[r] = fmaf(k2, xv.z, ak[r]); ak[r] = fmaf(k3, xv.w, ak[r]);
                }
                if (has7) {
                    float4 xv = ((const float4*)&xs[(iq + 48) * ND])[cb];
                    aq[6] = fmaf(q0, xv.x, aq[6]); aq[6] = fmaf(q1, xv.y, aq[6]);
                    aq[6] = fmaf(q2, xv.z, aq[6]); aq[6] = fmaf(q3, xv.w, aq[6]);
                    ak[6] = fmaf(k0, xv.x, ak[6]); ak[6] = fmaf(k1, xv.y, ak[6]);
                    ak[6] = fmaf(k2, xv.z, ak[6]); ak[6] = fmaf(k3, xv.w, ak[6]);
                }
            }
#pragma unroll
            for (int r = 0; r < 6; ++r) {
                qs[(iq + 8 * r) * ND + d] = aq[r] * LOG2E;
                ks[(iq + 8 * r) * ND + d] = ak[r] * LOG2E;
            }
            if (has7) {
                qs[(iq + 48) * ND + d] = aq[6] * LOG2E;
                ks[(iq + 48) * ND + d] = ak[6] * LOG2E;
            }
        }
        __syncthreads();

        // ---- phase 2: softmax-weighted sum; j-invariant reads hoisted ----
        // att[i,d] = sum_j 2^lrelu(q'+k') * x[j,d] / sum_j 2^lrelu(q'+k'),  q',k' pre-scaled by log2e
        {
            float qv[7], den[7], num[7];
#pragma unroll
            for (int r = 0; r < 7; ++r) { den[r] = 0.f; num[r] = 0.f; qv[r] = 0.f; }
#pragma unroll
            for (int r = 0; r < 6; ++r) qv[r] = qs[(iq + 8 * r) * ND + d];
            if (has7) qv[6] = qs[(iq + 48) * ND + d];

            for (int j = 0; j < NN; ++j) {
                float kj = ks[j * ND + d];
                float xj = xs[j * ND + d];
#pragma unroll
                for (int r = 0; r < 6; ++r) {
                    float z = qv[r] + kj;
                    z = fmaxf(z, 0.01f * z);            // leaky_relu (scale-invariant)
                    float w = __builtin_exp2f(z);       // v_exp_f32
                    den[r] += w;
                    num[r] = fmaf(w, xj, num[r]);
                }
                if (has7) {
                    float z = qv[6] + kj;
                    z = fmaxf(z, 0.01f * z);
                    float w = __builtin_exp2f(z);
                    den[6] += w;
                    num[6] = fmaf(w, xj, num[6]);
                }
            }
#pragma unroll
            for (int r = 0; r < 6; ++r) qs[(iq + 8 * r) * ND + d] = num[r] / den[r];
            if (has7) qs[(iq + 48) * ND + d] = num[6] / den[6];
        }
        __syncthreads();

        // ---- phase 3: output GEMM y = att @ Wl + bl, weights hoisted ----
        {
            float ao[7];
            const float bo = (L == 0) ? bo1 : bo2;
#pragma unroll
            for (int r = 0; r < 7; ++r) ao[r] = bo;
#pragma unroll
            for (int cb = 0; cb < 16; ++cb) {
                unsigned int p0 = wo32[(2 * cb + 0) * ND + d];   // cols 4cb, 4cb+1
                unsigned int p1 = wo32[(2 * cb + 1) * ND + d];   // cols 4cb+2, 4cb+3
                float c0 = bflo(p0), c1 = bfhi(p0), c2 = bflo(p1), c3 = bfhi(p1);
#pragma unroll
                for (int r = 0; r < 6; ++r) {
                    float4 av = ((const float4*)&qs[(iq + 8 * r) * ND])[cb];
                    ao[r] = fmaf(c0, av.x, ao[r]); ao[r] = fmaf(c1, av.y, ao[r]);
                    ao[r] = fmaf(c2, av.z, ao[r]); ao[r] = fmaf(c3, av.w, ao[r]);
                }
                if (has7) {
                    float4 av = ((const float4*)&qs[(iq + 48) * ND])[cb];
                    ao[6] = fmaf(c0, av.x, ao[6]); ao[6] = fmaf(c1, av.y, ao[6]);
                    ao[6] = fmaf(c2, av.z, ao[6]); ao[6] = fmaf(c3, av.w, ao[6]);
                }
            }
            if (L == 0) {
#pragma unroll
                for (int r = 0; r < 6; ++r) xs[(iq + 8 * r) * ND + d] = ao[r];
                if (has7) xs[(iq + 48) * ND + d] = ao[6];
                __syncthreads();
            } else {
                const float e0 = embB[d];                        // embeddings[b,0,d]
#pragma unroll
                for (int r = 0; r < 7; ++r) {
                    int i = iq + 8 * r;
                    if (r == 6 && !has7) break;
                    float ie = embB[ND + i * ND + d];            // i_em[i,d]
                    float o  = fmaf(e0, ie, ao[r] + xs[i * ND + d]);
                    o = fmaxf(o, 0.01f * o);                     // final leaky_relu
                    out[((size_t)b * NN + i) * ND + d] = o;
                }
            }
        }
    }
}

extern "C" void kernel_launch(void* const* d_in, const int* in_sizes, int n_in,
                              void* d_out, int out_size, void* d_ws, size_t ws_size,
                              hipStream_t stream) {
    const float* emb = (const float*)d_in[0];
    const float* wa1 = (const float*)d_in[1];
    const float* ba1 = (const float*)d_in[2];
    const float* wa2 = (const float*)d_in[3];
    const float* ba2 = (const float*)d_in[4];
    const float* w1  = (const float*)d_in[5];
    const float* b1  = (const float*)d_in[6];
    const float* w2  = (const float*)d_in[7];
    const float* b2  = (const float*)d_in[8];
    float* out = (float*)d_out;

    att2_kernel<<<NB, 512, 0, stream>>>(emb, wa1, ba1, wa2, ba2, w1, b1, w2, b2, out);
}

// Round 4
// 126.333 us; speedup vs baseline: 1.3192x; 1.1785x over previous
//
#include <hip/hip_runtime.h>

#define NB 512
#define NN 50
#define ND 64
#define LOG2E 1.44269504088896340736f

__device__ __forceinline__ float bflo(unsigned int w) {
    union { unsigned int i; float f; } v; v.i = w << 16; return v.f;
}
__device__ __forceinline__ float bfhi(unsigned int w) {
    union { unsigned int i; float f; } v; v.i = w & 0xFFFF0000u; return v.f;
}
// fp32 -> bf16 bits, round-to-nearest-even
__device__ __forceinline__ unsigned int f2bfbits(float f) {
    union { float f; unsigned int i; } v; v.f = f;
    unsigned int x = v.i;
    return (x + 0x7FFFu + ((x >> 16) & 1u)) >> 16;
}

// One block per batch, 512 threads (8 waves): d = tid&63, iq = tid>>6 (0..7).
// Thread owns rows i = iq + 8r; r=0..5 always valid, r=6 iff iq<2 (rows 48,49).
//
// Softmax trick: exp(lrelu(q+k)) = max(exp(q)exp(k), exp(.01q)exp(.01k))
// (exp monotone + lrelu = max(z,.01z)) -> all transcendentals hoisted per-row.
__global__ __launch_bounds__(512, 4)
void att2_kernel(const float* __restrict__ emb,
                 const float* __restrict__ wa1, const float* __restrict__ ba1,
                 const float* __restrict__ wa2, const float* __restrict__ ba2,
                 const float* __restrict__ w1,  const float* __restrict__ b1,
                 const float* __restrict__ w2,  const float* __restrict__ b2,
                 float* __restrict__ out)
{
    __shared__ __align__(16) float xs[NN * ND];   // layer input x
    __shared__ __align__(16) float qs[NN * ND];   // att result (phase2 -> phase3)
    __shared__ unsigned int keu[NN * ND];         // hi16=bf16(exp2(k')), lo16=bf16(exp2(.01k'))
    __shared__ unsigned int wqk[ND * ND];         // lo16=bf16(Wa1), hi16=bf16(Wa2)
    __shared__ unsigned int wo32[(ND / 2) * ND];  // pair-packed bf16(W1|W2)

    const int b   = blockIdx.x;
    const int tid = threadIdx.x;
    const int d   = tid & 63;
    const int iq  = tid >> 6;
    const bool has7 = (iq < 2);

    const float* embB = emb + (size_t)b * (NN + 1) * ND;

    // ---- phase 0: stage x, pack Wa1/Wa2, pack W1 ----
    {
        const float4* s4 = (const float4*)(embB + ND);
        float4* d4 = (float4*)xs;
        for (int idx = tid; idx < (NN * ND) / 4; idx += 512) d4[idx] = s4[idx];
    }
    for (int idx = tid; idx < ND * ND; idx += 512)
        wqk[idx] = (f2bfbits(wa2[idx]) << 16) | f2bfbits(wa1[idx]);
    for (int idx = tid; idx < (ND / 2) * ND; idx += 512) {
        int c2 = idx >> 6, dd = idx & 63;
        wo32[idx] = (f2bfbits(w1[(2 * c2 + 1) * ND + dd]) << 16)
                  |  f2bfbits(w1[(2 * c2) * ND + dd]);
    }
    __syncthreads();

    const float bq  = ba1[d];
    const float bk  = ba2[d];
    const float bo1 = b1[d];
    const float bo2 = b2[d];

    float Eq[7], eq[7];                 // per-owned-row q-side exps (registers)

    for (int L = 0; L < 2; ++L) {
        // ---- restage wo32 = W2 for L1 (old readers done >=1 barrier ago;
        //      next readers >=2 barriers ahead) ----
        if (L == 1) {
            for (int idx = tid; idx < (ND / 2) * ND; idx += 512) {
                int c2 = idx >> 6, dd = idx & 63;
                wo32[idx] = (f2bfbits(w2[(2 * c2 + 1) * ND + dd]) << 16)
                          |  f2bfbits(w2[(2 * c2) * ND + dd]);
            }
        }

        // ---- phase 1: q/k GEMM (register-blocked rows, hoisted weights),
        //      then per-row exp precompute ----
        {
            float aq[7], ak[7];
#pragma unroll
            for (int r = 0; r < 7; ++r) { aq[r] = bq; ak[r] = bk; }
#pragma unroll
            for (int cb = 0; cb < 16; ++cb) {
                unsigned int u0 = wqk[(4 * cb + 0) * ND + d];
                unsigned int u1 = wqk[(4 * cb + 1) * ND + d];
                unsigned int u2 = wqk[(4 * cb + 2) * ND + d];
                unsigned int u3 = wqk[(4 * cb + 3) * ND + d];
                float q0 = bflo(u0), q1 = bflo(u1), q2 = bflo(u2), q3 = bflo(u3);
                float k0 = bfhi(u0), k1 = bfhi(u1), k2 = bfhi(u2), k3 = bfhi(u3);
#pragma unroll
                for (int r = 0; r < 6; ++r) {
                    float4 xv = ((const float4*)&xs[(iq + 8 * r) * ND])[cb];
                    aq[r] = fmaf(q0, xv.x, aq[r]); aq[r] = fmaf(q1, xv.y, aq[r]);
                    aq[r] = fmaf(q2, xv.z, aq[r]); aq[r] = fmaf(q3, xv.w, aq[r]);
                    ak[r] = fmaf(k0, xv.x, ak[r]); ak[r] = fmaf(k1, xv.y, ak[r]);
                    ak[r] = fmaf(k2, xv.z, ak[r]); ak[r] = fmaf(k3, xv.w, ak[r]);
                }
                if (has7) {
                    float4 xv = ((const float4*)&xs[(iq + 48) * ND])[cb];
                    aq[6] = fmaf(q0, xv.x, aq[6]); aq[6] = fmaf(q1, xv.y, aq[6]);
                    aq[6] = fmaf(q2, xv.z, aq[6]); aq[6] = fmaf(q3, xv.w, aq[6]);
                    ak[6] = fmaf(k0, xv.x, ak[6]); ak[6] = fmaf(k1, xv.y, ak[6]);
                    ak[6] = fmaf(k2, xv.z, ak[6]); ak[6] = fmaf(k3, xv.w, ak[6]);
                }
            }
#pragma unroll
            for (int r = 0; r < 7; ++r) {
                if (r == 6 && !has7) break;
                int i = iq + 8 * r;
                float qp = aq[r] * LOG2E;
                float kp = ak[r] * LOG2E;
                Eq[r] = __builtin_exp2f(qp);
                eq[r] = __builtin_exp2f(0.01f * qp);
                float Ek = __builtin_exp2f(kp);
                float ek = __builtin_exp2f(0.01f * kp);
                keu[i * ND + d] = (f2bfbits(Ek) << 16) | f2bfbits(ek);
            }
        }
        __syncthreads();

        // ---- phase 2: softmax-weighted sum, no transcendentals ----
        // w = max(Eq*Ek, eq*ek);  att = sum w*x / sum w
        {
            float den[7], num[7];
#pragma unroll
            for (int r = 0; r < 7; ++r) { den[r] = 0.f; num[r] = 0.f; }

            for (int j = 0; j < NN; ++j) {
                unsigned int kw = keu[j * ND + d];
                float xj = xs[j * ND + d];
                float Ek = bfhi(kw);
                float ek = bflo(kw);
#pragma unroll
                for (int r = 0; r < 6; ++r) {
                    float w = fmaxf(Eq[r] * Ek, eq[r] * ek);
                    den[r] += w;
                    num[r] = fmaf(w, xj, num[r]);
                }
                if (has7) {
                    float w = fmaxf(Eq[6] * Ek, eq[6] * ek);
                    den[6] += w;
                    num[6] = fmaf(w, xj, num[6]);
                }
            }
#pragma unroll
            for (int r = 0; r < 6; ++r) qs[(iq + 8 * r) * ND + d] = num[r] / den[r];
            if (has7) qs[(iq + 48) * ND + d] = num[6] / den[6];
        }
        __syncthreads();

        // ---- phase 3: output GEMM y = att @ Wl + bl ----
        {
            float ao[7];
            const float bo = (L == 0) ? bo1 : bo2;
#pragma unroll
            for (int r = 0; r < 7; ++r) ao[r] = bo;
#pragma unroll
            for (int cb = 0; cb < 16; ++cb) {
                unsigned int p0 = wo32[(2 * cb + 0) * ND + d];
                unsigned int p1 = wo32[(2 * cb + 1) * ND + d];
                float c0 = bflo(p0), c1 = bfhi(p0), c2 = bflo(p1), c3 = bfhi(p1);
#pragma unroll
                for (int r = 0; r < 6; ++r) {
                    float4 av = ((const float4*)&qs[(iq + 8 * r) * ND])[cb];
                    ao[r] = fmaf(c0, av.x, ao[r]); ao[r] = fmaf(c1, av.y, ao[r]);
                    ao[r] = fmaf(c2, av.z, ao[r]); ao[r] = fmaf(c3, av.w, ao[r]);
                }
                if (has7) {
                    float4 av = ((const float4*)&qs[(iq + 48) * ND])[cb];
                    ao[6] = fmaf(c0, av.x, ao[6]); ao[6] = fmaf(c1, av.y, ao[6]);
                    ao[6] = fmaf(c2, av.z, ao[6]); ao[6] = fmaf(c3, av.w, ao[6]);
                }
            }
            if (L == 0) {
#pragma unroll
                for (int r = 0; r < 6; ++r) xs[(iq + 8 * r) * ND + d] = ao[r];
                if (has7) xs[(iq + 48) * ND + d] = ao[6];
                __syncthreads();
            } else {
                const float e0 = embB[d];                    // embeddings[b,0,d]
#pragma unroll
                for (int r = 0; r < 7; ++r) {
                    int i = iq + 8 * r;
                    if (r == 6 && !has7) break;
                    float ie = embB[ND + i * ND + d];        // i_em[i,d]
                    float o  = fmaf(e0, ie, ao[r] + xs[i * ND + d]);
                    o = fmaxf(o, 0.01f * o);                 // final leaky_relu
                    out[((size_t)b * NN + i) * ND + d] = o;
                }
            }
        }
    }
}

extern "C" void kernel_launch(void* const* d_in, const int* in_sizes, int n_in,
                              void* d_out, int out_size, void* d_ws, size_t ws_size,
                              hipStream_t stream) {
    const float* emb = (const float*)d_in[0];
    const float* wa1 = (const float*)d_in[1];
    const float* ba1 = (const float*)d_in[2];
    const float* wa2 = (const float*)d_in[3];
    const float* ba2 = (const float*)d_in[4];
    const float* w1  = (const float*)d_in[5];
    const float* b1  = (const float*)d_in[6];
    const float* w2  = (const float*)d_in[7];
    const float* b2  = (const float*)d_in[8];
    float* out = (float*)d_out;

    att2_kernel<<<NB, 512, 0, stream>>>(emb, wa1, ba1, wa2, ba2, w1, b1, w2, b2, out);
}

// Round 5
// 123.884 us; speedup vs baseline: 1.3452x; 1.0198x over previous
//
#include <hip/hip_runtime.h>

#define NB 512
#define NN 50
#define ND 64
#define LOG2E 1.44269504088896340736f

typedef short bf16x8 __attribute__((ext_vector_type(8)));
typedef float f32x4  __attribute__((ext_vector_type(4)));

__device__ __forceinline__ float bfu(unsigned short u) {
    union { unsigned int i; float f; } v; v.i = ((unsigned int)u) << 16; return v.f;
}
__device__ __forceinline__ float bflo(unsigned int w) {
    union { unsigned int i; float f; } v; v.i = w << 16; return v.f;
}
__device__ __forceinline__ float bfhi(unsigned int w) {
    union { unsigned int i; float f; } v; v.i = w & 0xFFFF0000u; return v.f;
}
// fp32 -> bf16 bits, round-to-nearest-even
__device__ __forceinline__ unsigned int f2bfbits(float f) {
    union { float f; unsigned int i; } v; v.f = f;
    unsigned int x = v.i;
    return (x + 0x7FFFu + ((x >> 16) & 1u)) >> 16;
}

// One block per batch, 512 threads = 8 waves.
// GEMM phases (1,3) use mfma_f32_16x16x32_bf16: M=50 padded to 64 -> 4x4 tiles
// of 16x16; wave w owns tiles (tm = w>>1, tn in {2(w&1), 2(w&1)+1}); K=64 = 2 steps.
// Layouts (HW-verified): A[m=lane&15][k=(lane>>4)*8+j]; B[k][n=lane&15] (same k);
// C/D: row=(lane>>4)*4+reg, col=lane&15.
// Phase 2 (elementwise softmax over j, per (i,d)): thread (iq=tid>>6, d=tid&63)
// owns rows i = iq+8r. rho-trick: w = Eq*max(Ek, rho*ek), rho = exp2(-0.99*q');
// Eq cancels in num/den, so only rho is needed on the q side.
__global__ __launch_bounds__(512, 4)
void att2_kernel(const float* __restrict__ emb,
                 const float* __restrict__ wa1, const float* __restrict__ ba1,
                 const float* __restrict__ wa2, const float* __restrict__ ba2,
                 const float* __restrict__ w1,  const float* __restrict__ b1,
                 const float* __restrict__ w2,  const float* __restrict__ b2,
                 float* __restrict__ out)
{
    // x double-buffer (bf16, row stride 72 for bank spread, rows 50-63 zero pad)
    __shared__ __align__(16) unsigned short xa[64 * 72];   // layer input x
    __shared__ __align__(16) unsigned short xb[64 * 72];   // att (phase2 -> phase3 A)
    __shared__ __align__(16) unsigned short wa1t[64 * 64]; // Wa1^T: [n][k]
    __shared__ __align__(16) unsigned short wa2t[64 * 64]; // Wa2^T: [n][k]
    __shared__ __align__(16) unsigned short wot[64 * 64];  // W1^T then W2^T
    __shared__ unsigned int   keu[NN * ND];                // hi=bf16(Ek), lo=bf16(ek)
    __shared__ unsigned short qrho[NN * ND];               // bf16(rho)

    const int b    = blockIdx.x;
    const int tid  = threadIdx.x;
    const int w    = tid >> 6;        // wave id 0..7
    const int lane = tid & 63;
    const int ln   = lane & 15;       // MFMA col-in-tile / B n
    const int qd   = lane >> 4;       // MFMA quad
    const int tm   = w >> 1;          // M-tile 0..3
    const int tn0  = (w & 1) * 2;     // first N-tile (owns tn0, tn0+1)
    const int d    = lane;            // phase-2 column
    const int iq   = w;               // phase-2 row group
    const bool has7 = (iq < 2);

    const float* embB = emb + (size_t)b * (NN + 1) * ND;

    // ---- phase 0: stage x (fp32->bf16), zero pads, stage W^T ----
    for (int u = tid; u < (NN * ND) / 2; u += 512) {
        float2 v = *(const float2*)(embB + ND + 2 * u);
        int i = (2 * u) >> 6, c = (2 * u) & 63;
        *(unsigned int*)&xa[i * 72 + c] = (f2bfbits(v.y) << 16) | f2bfbits(v.x);
    }
    for (int u = tid; u < 14 * 72; u += 512) {       // rows 50..63
        xa[NN * 72 + u] = 0;
        xb[NN * 72 + u] = 0;
    }
    for (int u = tid; u < ND * ND; u += 512) {
        int k = u >> 6, n = u & 63;
        wa1t[n * 64 + k] = (unsigned short)f2bfbits(wa1[u]);
        wa2t[n * 64 + k] = (unsigned short)f2bfbits(wa2[u]);
        wot [n * 64 + k] = (unsigned short)f2bfbits(w1[u]);
    }
    __syncthreads();

    // per-wave tile biases (constant across layers)
    const float bq0 = ba1[tn0 * 16 + ln], bq1 = ba1[(tn0 + 1) * 16 + ln];
    const float bk0 = ba2[tn0 * 16 + ln], bk1 = ba2[(tn0 + 1) * 16 + ln];

    for (int L = 0; L < 2; ++L) {
        // ---- restage wot = W2^T for L1 (prev readers done >=1 barrier ago,
        //      next readers >=2 barriers ahead) ----
        if (L == 1) {
            for (int u = tid; u < ND * ND; u += 512) {
                int k = u >> 6, n = u & 63;
                wot[n * 64 + k] = (unsigned short)f2bfbits(w2[u]);
            }
        }

        // ---- phase 1: q/k GEMM on MFMA + exp epilogue ----
        {
            const bf16x8 a0 = *(const bf16x8*)&xa[(tm * 16 + ln) * 72 + qd * 8];
            const bf16x8 a1 = *(const bf16x8*)&xa[(tm * 16 + ln) * 72 + 32 + qd * 8];

            f32x4 accq0 = {bq0, bq0, bq0, bq0};
            f32x4 accq1 = {bq1, bq1, bq1, bq1};
            f32x4 acck0 = {bk0, bk0, bk0, bk0};
            f32x4 acck1 = {bk1, bk1, bk1, bk1};

            bf16x8 bf_;
            bf_ = *(const bf16x8*)&wa1t[(tn0 * 16 + ln) * 64 + qd * 8];
            accq0 = __builtin_amdgcn_mfma_f32_16x16x32_bf16(a0, bf_, accq0, 0, 0, 0);
            bf_ = *(const bf16x8*)&wa1t[(tn0 * 16 + ln) * 64 + 32 + qd * 8];
            accq0 = __builtin_amdgcn_mfma_f32_16x16x32_bf16(a1, bf_, accq0, 0, 0, 0);
            bf_ = *(const bf16x8*)&wa1t[((tn0 + 1) * 16 + ln) * 64 + qd * 8];
            accq1 = __builtin_amdgcn_mfma_f32_16x16x32_bf16(a0, bf_, accq1, 0, 0, 0);
            bf_ = *(const bf16x8*)&wa1t[((tn0 + 1) * 16 + ln) * 64 + 32 + qd * 8];
            accq1 = __builtin_amdgcn_mfma_f32_16x16x32_bf16(a1, bf_, accq1, 0, 0, 0);

            bf_ = *(const bf16x8*)&wa2t[(tn0 * 16 + ln) * 64 + qd * 8];
            acck0 = __builtin_amdgcn_mfma_f32_16x16x32_bf16(a0, bf_, acck0, 0, 0, 0);
            bf_ = *(const bf16x8*)&wa2t[(tn0 * 16 + ln) * 64 + 32 + qd * 8];
            acck0 = __builtin_amdgcn_mfma_f32_16x16x32_bf16(a1, bf_, acck0, 0, 0, 0);
            bf_ = *(const bf16x8*)&wa2t[((tn0 + 1) * 16 + ln) * 64 + qd * 8];
            acck1 = __builtin_amdgcn_mfma_f32_16x16x32_bf16(a0, bf_, acck1, 0, 0, 0);
            bf_ = *(const bf16x8*)&wa2t[((tn0 + 1) * 16 + ln) * 64 + 32 + qd * 8];
            acck1 = __builtin_amdgcn_mfma_f32_16x16x32_bf16(a1, bf_, acck1, 0, 0, 0);

#pragma unroll
            for (int t = 0; t < 2; ++t) {
                const int dcol = (tn0 + t) * 16 + ln;
                const f32x4 qa = t ? accq1 : accq0;
                const f32x4 ka = t ? acck1 : acck0;
#pragma unroll
                for (int reg = 0; reg < 4; ++reg) {
                    const int i = tm * 16 + qd * 4 + reg;
                    if (i < NN) {
                        float rho = __builtin_exp2f(qa[reg] * (-0.99f * LOG2E));
                        qrho[i * 64 + dcol] = (unsigned short)f2bfbits(rho);
                        float kp = ka[reg] * LOG2E;
                        unsigned int Ek = f2bfbits(__builtin_exp2f(kp));
                        unsigned int ek = f2bfbits(__builtin_exp2f(0.01f * kp));
                        keu[i * 64 + dcol] = (Ek << 16) | ek;
                    }
                }
            }
        }
        __syncthreads();

        // ---- phase 2: softmax-weighted sum (VALU), att -> xb (bf16) ----
        {
            float rho[7], num[7], den[7];
#pragma unroll
            for (int r = 0; r < 7; ++r) { rho[r] = 0.f; num[r] = 0.f; den[r] = 0.f; }
#pragma unroll
            for (int r = 0; r < 6; ++r) rho[r] = bfu(qrho[(iq + 8 * r) * 64 + d]);
            if (has7) rho[6] = bfu(qrho[(iq + 48) * 64 + d]);

            for (int j = 0; j < NN; ++j) {
                unsigned int kw = keu[j * 64 + d];
                float xj = bfu(xa[j * 72 + d]);
                float Ek = bfhi(kw);
                float ek = bflo(kw);
#pragma unroll
                for (int r = 0; r < 6; ++r) {
                    float wv = fmaxf(Ek, rho[r] * ek);
                    den[r] += wv;
                    num[r] = fmaf(wv, xj, num[r]);
                }
                if (has7) {
                    float wv = fmaxf(Ek, rho[6] * ek);
                    den[6] += wv;
                    num[6] = fmaf(wv, xj, num[6]);
                }
            }
#pragma unroll
            for (int r = 0; r < 6; ++r)
                xb[(iq + 8 * r) * 72 + d] = (unsigned short)f2bfbits(num[r] / den[r]);
            if (has7)
                xb[(iq + 48) * 72 + d] = (unsigned short)f2bfbits(num[6] / den[6]);
        }
        __syncthreads();

        // ---- phase 3: y = att @ Wl + bl on MFMA ----
        {
            const bf16x8 c0 = *(const bf16x8*)&xb[(tm * 16 + ln) * 72 + qd * 8];
            const bf16x8 c1 = *(const bf16x8*)&xb[(tm * 16 + ln) * 72 + 32 + qd * 8];
            const float* bo = L ? b2 : b1;
            const float bo0 = bo[tn0 * 16 + ln];
            const float bo1 = bo[(tn0 + 1) * 16 + ln];
            f32x4 y0 = {bo0, bo0, bo0, bo0};
            f32x4 y1 = {bo1, bo1, bo1, bo1};

            bf16x8 bf_;
            bf_ = *(const bf16x8*)&wot[(tn0 * 16 + ln) * 64 + qd * 8];
            y0 = __builtin_amdgcn_mfma_f32_16x16x32_bf16(c0, bf_, y0, 0, 0, 0);
            bf_ = *(const bf16x8*)&wot[(tn0 * 16 + ln) * 64 + 32 + qd * 8];
            y0 = __builtin_amdgcn_mfma_f32_16x16x32_bf16(c1, bf_, y0, 0, 0, 0);
            bf_ = *(const bf16x8*)&wot[((tn0 + 1) * 16 + ln) * 64 + qd * 8];
            y1 = __builtin_amdgcn_mfma_f32_16x16x32_bf16(c0, bf_, y1, 0, 0, 0);
            bf_ = *(const bf16x8*)&wot[((tn0 + 1) * 16 + ln) * 64 + 32 + qd * 8];
            y1 = __builtin_amdgcn_mfma_f32_16x16x32_bf16(c1, bf_, y1, 0, 0, 0);

            if (L == 0) {
                // att_value1 -> xa (becomes L1 input x and the epilogue residual)
#pragma unroll
                for (int t = 0; t < 2; ++t) {
                    const int dcol = (tn0 + t) * 16 + ln;
                    const f32x4 y = t ? y1 : y0;
#pragma unroll
                    for (int reg = 0; reg < 4; ++reg) {
                        const int i = tm * 16 + qd * 4 + reg;
                        if (i < NN)
                            xa[i * 72 + dcol] = (unsigned short)f2bfbits(y[reg]);
                    }
                }
                __syncthreads();
            } else {
                // epilogue: out = lrelu(e0*i_em + y + att1)
#pragma unroll
                for (int t = 0; t < 2; ++t) {
                    const int dcol = (tn0 + t) * 16 + ln;
                    const float e0 = embB[dcol];
                    const f32x4 y = t ? y1 : y0;
#pragma unroll
                    for (int reg = 0; reg < 4; ++reg) {
                        const int i = tm * 16 + qd * 4 + reg;
                        if (i < NN) {
                            float ie   = embB[ND + i * ND + dcol];
                            float att1 = bfu(xa[i * 72 + dcol]);
                            float o    = fmaf(e0, ie, y[reg] + att1);
                            o = fmaxf(o, 0.01f * o);
                            out[((size_t)b * NN + i) * ND + dcol] = o;
                        }
                    }
                }
            }
        }
    }
}

extern "C" void kernel_launch(void* const* d_in, const int* in_sizes, int n_in,
                              void* d_out, int out_size, void* d_ws, size_t ws_size,
                              hipStream_t stream) {
    const float* emb = (const float*)d_in[0];
    const float* wa1 = (const float*)d_in[1];
    const float* ba1 = (const float*)d_in[2];
    const float* wa2 = (const float*)d_in[3];
    const float* ba2 = (const float*)d_in[4];
    const float* w1  = (const float*)d_in[5];
    const float* b1  = (const float*)d_in[6];
    const float* w2  = (const float*)d_in[7];
    const float* b2  = (const float*)d_in[8];
    float* out = (float*)d_out;

    att2_kernel<<<NB, 512, 0, stream>>>(emb, wa1, ba1, wa2, ba2, w1, b1, w2, b2, out);
}

// Round 6
// 105.475 us; speedup vs baseline: 1.5800x; 1.1745x over previous
//
#include <hip/hip_runtime.h>

#define NB 512
#define NN 50
#define ND 64
#define LOG2E 1.44269504088896340736f

typedef short bf16x8 __attribute__((ext_vector_type(8)));
typedef float f32x4  __attribute__((ext_vector_type(4)));

__device__ __forceinline__ float bfu(unsigned short u) {
    union { unsigned int i; float f; } v; v.i = ((unsigned int)u) << 16; return v.f;
}
__device__ __forceinline__ float bflo(unsigned int w) {
    union { unsigned int i; float f; } v; v.i = w << 16; return v.f;
}
__device__ __forceinline__ float bfhi(unsigned int w) {
    union { unsigned int i; float f; } v; v.i = w & 0xFFFF0000u; return v.f;
}
// fp32 -> bf16 bits, round-to-nearest-even
__device__ __forceinline__ unsigned int f2bfbits(float f) {
    union { float f; unsigned int i; } v; v.f = f;
    unsigned int x = v.i;
    return (x + 0x7FFFu + ((x >> 16) & 1u)) >> 16;
}

// One block per batch, 1024 threads = 16 waves (2 blocks/CU = 32 waves/CU).
// MFMA 16x16x32_bf16, M padded 50->64: 4x4 tile grid, ONE tile per wave:
//   tm = w>>2, tn = w&3.  K=64 = 2 MFMA steps.
// All LDS 2D arrays use row stride 72 shorts (144 B): b128 fragment loads are
// bank-balanced (base 4*(ln+qd)%32 covers all 32 banks; stride 64 = 128 B puts
// every qd-group on the same 4 banks -> measured 9.6M conflict cycles in r5).
// rho-trick: w_ij = Eq*max(Ek, rho*ek), rho = exp2(-0.99*q'); Eq cancels.
// Epilogue: y staged fp32 in keu (dead after phase 2), then coalesced residual
// + store (r5's scattered 64B stores caused 3x WRITE_SIZE from partial-line RMW).
__global__ __launch_bounds__(1024, 8)
void att2_kernel(const float* __restrict__ emb,
                 const float* __restrict__ wa1, const float* __restrict__ ba1,
                 const float* __restrict__ wa2, const float* __restrict__ ba2,
                 const float* __restrict__ w1,  const float* __restrict__ b1,
                 const float* __restrict__ w2,  const float* __restrict__ b2,
                 float* __restrict__ out)
{
    __shared__ __align__(16) unsigned short xa[64 * 72];   // layer input x (bf16, rows 50-63 zero)
    __shared__ __align__(16) unsigned short xb[64 * 72];   // att (phase2 -> phase3 A)
    __shared__ __align__(16) unsigned short wa1t[64 * 72]; // Wa1^T [n][k], padded
    __shared__ __align__(16) unsigned short wa2t[64 * 72]; // Wa2^T [n][k], padded
    __shared__ __align__(16) unsigned short wot[64 * 72];  // W1^T then W2^T, padded
    __shared__ __align__(16) unsigned int   keu[NN * ND];  // hi=bf16(Ek), lo=bf16(ek); reused fp32 y in L1 ph3
    __shared__ unsigned short qrho[NN * ND];               // bf16(rho)

    const int b    = blockIdx.x;
    const int tid  = threadIdx.x;
    const int w    = tid >> 6;        // wave id 0..15
    const int lane = tid & 63;
    const int ln   = lane & 15;       // MFMA m/n within tile
    const int qd   = lane >> 4;       // MFMA quad
    const int tm   = w >> 2;          // M-tile 0..3
    const int tn   = w & 3;           // N-tile 0..3
    const int d    = lane;            // phase-2 column
    const int iq   = w;               // phase-2 row group (0..15)
    const bool has3 = (iq < 2);       // row iq+48 valid

    const float* embB = emb + (size_t)b * (NN + 1) * ND;

    // ---- phase 0: stage x (fp32->bf16), zero pads, stage W^T (padded rows) ----
    for (int u = tid; u < (NN * ND) / 2; u += 1024) {
        float2 v = *(const float2*)(embB + ND + 2 * u);
        int i = (2 * u) >> 6, c = (2 * u) & 63;
        *(unsigned int*)&xa[i * 72 + c] = (f2bfbits(v.y) << 16) | f2bfbits(v.x);
    }
    for (int u = tid; u < 14 * 72; u += 1024) {      // rows 50..63
        xa[NN * 72 + u] = 0;
        xb[NN * 72 + u] = 0;
    }
    for (int u = tid; u < ND * ND; u += 1024) {
        int k = u >> 6, n = u & 63;
        wa1t[n * 72 + k] = (unsigned short)f2bfbits(wa1[u]);
        wa2t[n * 72 + k] = (unsigned short)f2bfbits(wa2[u]);
        wot [n * 72 + k] = (unsigned short)f2bfbits(w1[u]);
    }
    __syncthreads();

    const float bq = ba1[tn * 16 + ln];
    const float bk = ba2[tn * 16 + ln];

    for (int L = 0; L < 2; ++L) {
        // ---- restage wot = W2^T for L1 (prev readers finished >=1 barrier ago,
        //      next readers are 2 barriers ahead) ----
        if (L == 1) {
            for (int u = tid; u < ND * ND; u += 1024) {
                int k = u >> 6, n = u & 63;
                wot[n * 72 + k] = (unsigned short)f2bfbits(w2[u]);
            }
        }

        // ---- phase 1: q/k GEMM on MFMA (1 tile/wave) + exp epilogue ----
        {
            const bf16x8 a0 = *(const bf16x8*)&xa[(tm * 16 + ln) * 72 + qd * 8];
            const bf16x8 a1 = *(const bf16x8*)&xa[(tm * 16 + ln) * 72 + 32 + qd * 8];

            f32x4 accq = {bq, bq, bq, bq};
            f32x4 acck = {bk, bk, bk, bk};

            bf16x8 bf_;
            bf_ = *(const bf16x8*)&wa1t[(tn * 16 + ln) * 72 + qd * 8];
            accq = __builtin_amdgcn_mfma_f32_16x16x32_bf16(a0, bf_, accq, 0, 0, 0);
            bf_ = *(const bf16x8*)&wa1t[(tn * 16 + ln) * 72 + 32 + qd * 8];
            accq = __builtin_amdgcn_mfma_f32_16x16x32_bf16(a1, bf_, accq, 0, 0, 0);
            bf_ = *(const bf16x8*)&wa2t[(tn * 16 + ln) * 72 + qd * 8];
            acck = __builtin_amdgcn_mfma_f32_16x16x32_bf16(a0, bf_, acck, 0, 0, 0);
            bf_ = *(const bf16x8*)&wa2t[(tn * 16 + ln) * 72 + 32 + qd * 8];
            acck = __builtin_amdgcn_mfma_f32_16x16x32_bf16(a1, bf_, acck, 0, 0, 0);

            const int dcol = tn * 16 + ln;
#pragma unroll
            for (int reg = 0; reg < 4; ++reg) {
                const int i = tm * 16 + qd * 4 + reg;
                if (i < NN) {
                    float rho = __builtin_exp2f(accq[reg] * (-0.99f * LOG2E));
                    qrho[i * 64 + dcol] = (unsigned short)f2bfbits(rho);
                    float kp = acck[reg] * LOG2E;
                    unsigned int Ek = f2bfbits(__builtin_exp2f(kp));
                    unsigned int ek = f2bfbits(__builtin_exp2f(0.01f * kp));
                    keu[i * 64 + dcol] = (Ek << 16) | ek;
                }
            }
        }
        __syncthreads();

        // ---- phase 2: softmax-weighted sum (VALU), 4 rows/thread, att -> xb ----
        {
            float rho[4], num[4], den[4];
#pragma unroll
            for (int r = 0; r < 4; ++r) { rho[r] = 0.f; num[r] = 0.f; den[r] = 0.f; }
#pragma unroll
            for (int r = 0; r < 3; ++r) rho[r] = bfu(qrho[(iq + 16 * r) * 64 + d]);
            if (has3) rho[3] = bfu(qrho[(iq + 48) * 64 + d]);

            for (int j = 0; j < NN; ++j) {
                unsigned int kw = keu[j * 64 + d];
                float xj = bfu(xa[j * 72 + d]);
                float Ek = bfhi(kw);
                float ek = bflo(kw);
#pragma unroll
                for (int r = 0; r < 3; ++r) {
                    float wv = fmaxf(Ek, rho[r] * ek);
                    den[r] += wv;
                    num[r] = fmaf(wv, xj, num[r]);
                }
                if (has3) {
                    float wv = fmaxf(Ek, rho[3] * ek);
                    den[3] += wv;
                    num[3] = fmaf(wv, xj, num[3]);
                }
            }
#pragma unroll
            for (int r = 0; r < 3; ++r)
                xb[(iq + 16 * r) * 72 + d] = (unsigned short)f2bfbits(num[r] / den[r]);
            if (has3)
                xb[(iq + 48) * 72 + d] = (unsigned short)f2bfbits(num[3] / den[3]);
        }
        __syncthreads();

        // ---- phase 3: y = att @ Wl + bl on MFMA (1 tile/wave) ----
        {
            const bf16x8 c0 = *(const bf16x8*)&xb[(tm * 16 + ln) * 72 + qd * 8];
            const bf16x8 c1 = *(const bf16x8*)&xb[(tm * 16 + ln) * 72 + 32 + qd * 8];
            const float* bo = L ? b2 : b1;
            const float bov = bo[tn * 16 + ln];
            f32x4 y = {bov, bov, bov, bov};

            bf16x8 bf_;
            bf_ = *(const bf16x8*)&wot[(tn * 16 + ln) * 72 + qd * 8];
            y = __builtin_amdgcn_mfma_f32_16x16x32_bf16(c0, bf_, y, 0, 0, 0);
            bf_ = *(const bf16x8*)&wot[(tn * 16 + ln) * 72 + 32 + qd * 8];
            y = __builtin_amdgcn_mfma_f32_16x16x32_bf16(c1, bf_, y, 0, 0, 0);

            const int dcol = tn * 16 + ln;
            if (L == 0) {
                // att_value1 -> xa (L1 input x AND the final residual)
#pragma unroll
                for (int reg = 0; reg < 4; ++reg) {
                    const int i = tm * 16 + qd * 4 + reg;
                    if (i < NN)
                        xa[i * 72 + dcol] = (unsigned short)f2bfbits(y[reg]);
                }
                __syncthreads();
            } else {
                // stage raw y (fp32) into keu (dead after phase 2), then
                // coalesced residual + store.
                float* keuF = (float*)keu;
#pragma unroll
                for (int reg = 0; reg < 4; ++reg) {
                    const int i = tm * 16 + qd * 4 + reg;
                    if (i < NN)
                        keuF[i * 64 + dcol] = y[reg];
                }
                __syncthreads();
                for (int idx = tid; idx < NN * ND; idx += 1024) {
                    const int i  = idx >> 6;
                    const int dd = idx & 63;
                    float e0   = embB[dd];               // embeddings[b,0,dd]
                    float ie   = embB[ND + idx];         // i_em[i,dd] (coalesced)
                    float att1 = bfu(xa[i * 72 + dd]);
                    float o    = fmaf(e0, ie, keuF[idx] + att1);
                    o = fmaxf(o, 0.01f * o);             // final leaky_relu
                    out[(size_t)b * (NN * ND) + idx] = o;
                }
            }
        }
    }
}

extern "C" void kernel_launch(void* const* d_in, const int* in_sizes, int n_in,
                              void* d_out, int out_size, void* d_ws, size_t ws_size,
                              hipStream_t stream) {
    const float* emb = (const float*)d_in[0];
    const float* wa1 = (const float*)d_in[1];
    const float* ba1 = (const float*)d_in[2];
    const float* wa2 = (const float*)d_in[3];
    const float* ba2 = (const float*)d_in[4];
    const float* w1  = (const float*)d_in[5];
    const float* b1  = (const float*)d_in[6];
    const float* w2  = (const float*)d_in[7];
    const float* b2  = (const float*)d_in[8];
    float* out = (float*)d_out;

    att2_kernel<<<NB, 1024, 0, stream>>>(emb, wa1, ba1, wa2, ba2, w1, b1, w2, b2, out);
}

// Round 7
// 98.533 us; speedup vs baseline: 1.6913x; 1.0705x over previous
//
#include <hip/hip_runtime.h>
#include <hip/hip_fp16.h>

#define NB 512
#define NN 50
#define ND 64
#define LOG2E 1.44269504088896340736f

typedef short bf16x8 __attribute__((ext_vector_type(8)));
typedef float f32x4  __attribute__((ext_vector_type(4)));
typedef _Float16 h2  __attribute__((ext_vector_type(2)));

// ---- manual LDS arena (bytes) ----
// xa   u16 [64][72]  9216 @ 0      : layer input x / att1 (bf16, MFMA-A rows)
// wa1t u16 [64][72]  9216 @ 9216   : Wa1^T [n][k]
// wa2t u16 [64][72]  9216 @ 18432  : Wa2^T [n][k]
// wot  u16 [64][72]  9216 @ 27648  : W1^T then W2^T
// Ekt  f16 [64][54]  6912 @ 36864  : exp(k) transposed [d][j]
// ekt  f16 [64][54]  6912 @ 43776  : exp(.01k) transposed
// xt   f16 [64][54]  6912 @ 50688  : x transposed [d][j]
// qrho f16 [50][66]  6600 @ 57600  : rho = exp(-.99q), [i][d]
// alias xb u16 [64][72] 9216 @ 36864 (Ekt+ekt dead; barrier before write)
// alias yF f32 [50][64] 12800 @ 50688 (xt+qrho dead in L1 phase 3)
#define OFF_XA    0
#define OFF_WA1T  9216
#define OFF_WA2T  18432
#define OFF_WOT   27648
#define OFF_EKT   36864
#define OFF_EKL   43776
#define OFF_XT    50688
#define OFF_QRHO  57600
#define SMEM_BYTES 64224

__device__ __forceinline__ float bfu(unsigned short u) {
    union { unsigned int i; float f; } v; v.i = ((unsigned int)u) << 16; return v.f;
}
__device__ __forceinline__ unsigned int f2bfbits(float f) {
    union { float f; unsigned int i; } v; v.f = f;
    unsigned int x = v.i;
    return (x + 0x7FFFu + ((x >> 16) & 1u)) >> 16;
}

// One block per batch, 1024 threads = 16 waves (2 blocks/CU).
// MFMA 16x16x32_bf16, M padded 50->64, 4x4 tile grid, 1 tile/wave.
// Phase 2 in packed f16 (v_pk_*): 2 j's per issue slot; softmax weight
// w_ij = Eq*max(Ek, rho*ek) with rho = exp2(-0.99*q'*log2e); Eq cancels.
__global__ __launch_bounds__(1024, 8)
void att2_kernel(const float* __restrict__ emb,
                 const float* __restrict__ wa1, const float* __restrict__ ba1,
                 const float* __restrict__ wa2, const float* __restrict__ ba2,
                 const float* __restrict__ w1,  const float* __restrict__ b1,
                 const float* __restrict__ w2,  const float* __restrict__ b2,
                 float* __restrict__ out)
{
    __shared__ __align__(16) unsigned char smem[SMEM_BYTES];
    unsigned short* xa   = (unsigned short*)(smem + OFF_XA);
    unsigned short* wa1t = (unsigned short*)(smem + OFF_WA1T);
    unsigned short* wa2t = (unsigned short*)(smem + OFF_WA2T);
    unsigned short* wot  = (unsigned short*)(smem + OFF_WOT);
    _Float16*       Ekt  = (_Float16*)(smem + OFF_EKT);
    _Float16*       ekt  = (_Float16*)(smem + OFF_EKL);
    _Float16*       xt   = (_Float16*)(smem + OFF_XT);
    _Float16*       qrho = (_Float16*)(smem + OFF_QRHO);
    unsigned short* xb   = (unsigned short*)(smem + OFF_EKT);   // alias
    float*          yF   = (float*)(smem + OFF_XT);             // alias

    const int b    = blockIdx.x;
    const int tid  = threadIdx.x;
    const int w    = tid >> 6;        // wave 0..15
    const int lane = tid & 63;
    const int ln   = lane & 15;       // MFMA col/row-in-tile
    const int qd   = lane >> 4;       // MFMA quad
    const int tm   = w >> 2;          // M-tile
    const int tn   = w & 3;           // N-tile
    const int d    = lane;            // phase-2 column
    const int iq   = w;               // phase-2 row group
    const bool has3 = (iq < 2);       // row iq+48 valid

    const float* embB = emb + (size_t)b * (NN + 1) * ND;

    // ---- phase 0: stage x (bf16 rows + f16 transposed), W^T bf16 ----
    for (int u = tid; u < (NN * ND) / 2; u += 1024) {
        float2 v = *(const float2*)(embB + ND + 2 * u);
        int i = (2 * u) >> 6, c = (2 * u) & 63;
        *(unsigned int*)&xa[i * 72 + c] = (f2bfbits(v.y) << 16) | f2bfbits(v.x);
        xt[c * 54 + i]       = (_Float16)v.x;
        xt[(c + 1) * 54 + i] = (_Float16)v.y;
    }
    for (int u = tid; u < ND * ND; u += 1024) {
        int k = u >> 6, n = u & 63;
        wa1t[n * 72 + k] = (unsigned short)f2bfbits(wa1[u]);
        wa2t[n * 72 + k] = (unsigned short)f2bfbits(wa2[u]);
        wot [n * 72 + k] = (unsigned short)f2bfbits(w1[u]);
    }
    __syncthreads();

    const float bq = ba1[tn * 16 + ln];
    const float bk = ba2[tn * 16 + ln];

    for (int L = 0; L < 2; ++L) {
        if (L == 1) {   // restage W2^T (wot last read before previous barrier)
            for (int u = tid; u < ND * ND; u += 1024) {
                int k = u >> 6, n = u & 63;
                wot[n * 72 + k] = (unsigned short)f2bfbits(w2[u]);
            }
        }

        // ---- phase 1: q/k GEMM on MFMA + exp epilogue (transposed writes) ----
        {
            const bf16x8 a0 = *(const bf16x8*)&xa[(tm * 16 + ln) * 72 + qd * 8];
            const bf16x8 a1 = *(const bf16x8*)&xa[(tm * 16 + ln) * 72 + 32 + qd * 8];
            f32x4 accq = {bq, bq, bq, bq};
            f32x4 acck = {bk, bk, bk, bk};

            bf16x8 bf_;
            bf_ = *(const bf16x8*)&wa1t[(tn * 16 + ln) * 72 + qd * 8];
            accq = __builtin_amdgcn_mfma_f32_16x16x32_bf16(a0, bf_, accq, 0, 0, 0);
            bf_ = *(const bf16x8*)&wa1t[(tn * 16 + ln) * 72 + 32 + qd * 8];
            accq = __builtin_amdgcn_mfma_f32_16x16x32_bf16(a1, bf_, accq, 0, 0, 0);
            bf_ = *(const bf16x8*)&wa2t[(tn * 16 + ln) * 72 + qd * 8];
            acck = __builtin_amdgcn_mfma_f32_16x16x32_bf16(a0, bf_, acck, 0, 0, 0);
            bf_ = *(const bf16x8*)&wa2t[(tn * 16 + ln) * 72 + 32 + qd * 8];
            acck = __builtin_amdgcn_mfma_f32_16x16x32_bf16(a1, bf_, acck, 0, 0, 0);

            const int dcol = tn * 16 + ln;
#pragma unroll
            for (int reg = 0; reg < 4; ++reg) {
                const int i = tm * 16 + qd * 4 + reg;
                if (i < NN) {
                    float rho = __builtin_exp2f(accq[reg] * (-0.99f * LOG2E));
                    float kp  = acck[reg] * LOG2E;
                    qrho[i * 66 + dcol] = (_Float16)rho;
                    Ekt[dcol * 54 + i]  = (_Float16)__builtin_exp2f(kp);
                    ekt[dcol * 54 + i]  = (_Float16)__builtin_exp2f(0.01f * kp);
                }
            }
        }
        __syncthreads();

        // ---- phase 2: packed-f16 softmax-weighted sum, 2 j's per op ----
        float att[4];
        {
            h2 rho2[4], num2[4], den2[4];
#pragma unroll
            for (int r = 0; r < 4; ++r) {
                num2[r] = (h2)0.f; den2[r] = (h2)0.f; rho2[r] = (h2)0.f;
            }
#pragma unroll
            for (int r = 0; r < 3; ++r) {
                _Float16 rv = qrho[(iq + 16 * r) * 66 + d];
                rho2[r] = (h2){rv, rv};
            }
            if (has3) {
                _Float16 rv = qrho[(iq + 48) * 66 + d];
                rho2[3] = (h2){rv, rv};
            }

            const h2* EkP = (const h2*)&Ekt[d * 54];
            const h2* ekP = (const h2*)&ekt[d * 54];
            const h2* xP  = (const h2*)&xt[d * 54];
            for (int j2 = 0; j2 < NN / 2; ++j2) {
                h2 Ek2 = EkP[j2];
                h2 ek2 = ekP[j2];
                h2 x2  = xP[j2];
#pragma unroll
                for (int r = 0; r < 3; ++r) {
                    h2 wv = __builtin_elementwise_max(rho2[r] * ek2, Ek2);
                    den2[r] = den2[r] + wv;
                    num2[r] = wv * x2 + num2[r];        // contracts to v_pk_fma_f16
                }
                if (has3) {
                    h2 wv = __builtin_elementwise_max(rho2[3] * ek2, Ek2);
                    den2[3] = den2[3] + wv;
                    num2[3] = wv * x2 + num2[3];
                }
            }
#pragma unroll
            for (int r = 0; r < 4; ++r) {
                float nu = (float)num2[r].x + (float)num2[r].y;
                float de = (float)den2[r].x + (float)den2[r].y;
                att[r] = nu / de;
            }
        }
        __syncthreads();                 // Ekt/ekt fully read -> safe to alias
        {
#pragma unroll
            for (int r = 0; r < 3; ++r)
                xb[(iq + 16 * r) * 72 + d] = (unsigned short)f2bfbits(att[r]);
            if (has3)
                xb[(iq + 48) * 72 + d] = (unsigned short)f2bfbits(att[3]);
        }
        __syncthreads();

        // ---- phase 3: y = att @ Wl + bl on MFMA ----
        {
            const bf16x8 c0 = *(const bf16x8*)&xb[(tm * 16 + ln) * 72 + qd * 8];
            const bf16x8 c1 = *(const bf16x8*)&xb[(tm * 16 + ln) * 72 + 32 + qd * 8];
            const float bov = (L ? b2 : b1)[tn * 16 + ln];
            f32x4 y = {bov, bov, bov, bov};

            bf16x8 bf_;
            bf_ = *(const bf16x8*)&wot[(tn * 16 + ln) * 72 + qd * 8];
            y = __builtin_amdgcn_mfma_f32_16x16x32_bf16(c0, bf_, y, 0, 0, 0);
            bf_ = *(const bf16x8*)&wot[(tn * 16 + ln) * 72 + 32 + qd * 8];
            y = __builtin_amdgcn_mfma_f32_16x16x32_bf16(c1, bf_, y, 0, 0, 0);

            const int dcol = tn * 16 + ln;
            if (L == 0) {
                // att1 -> xa (bf16 rows: L1 MFMA-A + residual) and xt (f16 [d][j])
#pragma unroll
                for (int reg = 0; reg < 4; ++reg) {
                    const int i = tm * 16 + qd * 4 + reg;
                    if (i < NN) {
                        xa[i * 72 + dcol] = (unsigned short)f2bfbits(y[reg]);
                        xt[dcol * 54 + i] = (_Float16)y[reg];
                    }
                }
                __syncthreads();
            } else {
                // stage fp32 y (xt+qrho dead), then coalesced residual + store
#pragma unroll
                for (int reg = 0; reg < 4; ++reg) {
                    const int i = tm * 16 + qd * 4 + reg;
                    if (i < NN) yF[i * 64 + dcol] = y[reg];
                }
                __syncthreads();
                for (int idx = tid; idx < NN * ND; idx += 1024) {
                    const int i  = idx >> 6;
                    const int dd = idx & 63;
                    float e0   = embB[dd];
                    float ie   = embB[ND + idx];
                    float att1 = bfu(xa[i * 72 + dd]);
                    float o    = fmaf(e0, ie, yF[idx] + att1);
                    o = fmaxf(o, 0.01f * o);
                    out[(size_t)b * (NN * ND) + idx] = o;
                }
            }
        }
    }
}

extern "C" void kernel_launch(void* const* d_in, const int* in_sizes, int n_in,
                              void* d_out, int out_size, void* d_ws, size_t ws_size,
                              hipStream_t stream) {
    const float* emb = (const float*)d_in[0];
    const float* wa1 = (const float*)d_in[1];
    const float* ba1 = (const float*)d_in[2];
    const float* wa2 = (const float*)d_in[3];
    const float* ba2 = (const float*)d_in[4];
    const float* w1  = (const float*)d_in[5];
    const float* b1  = (const float*)d_in[6];
    const float* w2  = (const float*)d_in[7];
    const float* b2  = (const float*)d_in[8];
    float* out = (float*)d_out;

    att2_kernel<<<NB, 1024, 0, stream>>>(emb, wa1, ba1, wa2, ba2, w1, b1, w2, b2, out);
}